// Round 1
// baseline (105.595 us; speedup 1.0000x reference)
//
#include <hip/hip_runtime.h>
#include <hip/hip_bf16.h>

// Problem: BATCH=512, INPUT_SIZE=64, ALPHA_DIM=64
// out[b,a] = log-semiring chain over 63 steps, folded right-to-left as
// matrix-vector products in linear probability space.
//
// Q layout per (t,var): index o = (j>>2)*256 + a*4 + (j&3)
//   => lane a loads float4 at Qm4[g*64 + a] covering j=4g..4g+3  (coalesced)

#define NSTEP 63
#define AD 64

__global__ __launch_bounds__(256) void precompute_kernel(
    const float* __restrict__ theta, const float* __restrict__ ulpa,
    float* __restrict__ Q, float* __restrict__ pvar) {
  int t = blockIdx.x;  // 0..62
  __shared__ float tile[64][65];
  __shared__ float pa[64];
  int tid = threadIdx.x;

  // Load theta[0, t, :, :] (4096 floats) coalesced as float4 into LDS.
  const float4* th4 = (const float4*)(theta + t * 4096);
  #pragma unroll
  for (int k = 0; k < 4; ++k) {
    int i = tid + k * 256;       // float4 index 0..1023
    float4 v = th4[i];
    int a = i >> 4;              // (4i)>>6
    int j0 = (i & 15) * 4;       // (4i)&63
    tile[a][j0 + 0] = v.x;
    tile[a][j0 + 1] = v.y;
    tile[a][j0 + 2] = v.z;
    tile[a][j0 + 3] = v.w;
  }

  // softmax over ulpa[t, :] on wave 0
  if (tid < 64) {
    float v = ulpa[t * 64 + tid];
    float m = v;
    #pragma unroll
    for (int o = 32; o >= 1; o >>= 1) m = fmaxf(m, __shfl_xor(m, o));
    float e = __expf(v - m);
    float s = e;
    #pragma unroll
    for (int o = 32; o >= 1; o >>= 1) s += __shfl_xor(s, o);
    pa[tid] = e / s;
  }
  __syncthreads();

  // Write Q[t][var] in the [j/4][a][j%4] layout, coalesced stores.
  float* Q0 = Q + (t * 2 + 0) * 4096;
  float* Q1 = Q + (t * 2 + 1) * 4096;
  #pragma unroll
  for (int k = 0; k < 16; ++k) {
    int o = tid + k * 256;        // 0..4095
    int g = o >> 8;               // j>>2
    int rem = o & 255;
    int a = rem >> 2;
    int d = rem & 3;
    int j = g * 4 + d;
    float th = tile[a][j];
    float sig = 1.0f / (1.0f + __expf(-th));
    float w = pa[j];
    Q1[o] = sig * w;            // x-bit = 1: sigmoid(theta)
    Q0[o] = (1.0f - sig) * w;   // x-bit = 0: sigmoid(-theta)
  }

  // p variants from theta[0, 63, k, 0]
  if (t == 0 && tid < 64) {
    float th = theta[63 * 4096 + tid * 64 + 0];
    float sig = 1.0f / (1.0f + __expf(-th));
    pvar[64 + tid] = sig;         // var 1
    pvar[0 + tid]  = 1.0f - sig;  // var 0
  }
}

__global__ __launch_bounds__(64) void chain_kernel(
    const float* __restrict__ x, const float* __restrict__ Q,
    const float* __restrict__ pvar, float* __restrict__ out) {
  int b = blockIdx.x;     // 0..511
  int lane = threadIdx.x; // 0..63

  float xv = x[b * 64 + lane];
  unsigned long long mask = __ballot(xv != 0.0f);

  __shared__ __align__(16) float u_lds[64];

  int bit63 = (int)((mask >> 63) & 1ull);
  float u = pvar[bit63 * 64 + lane];
  float acc = 0.0f;

  for (int t = NSTEP - 1; t >= 0; --t) {
    int bit = (int)((mask >> t) & 1ull);
    const float4* Qm4 = (const float4*)(Q + (t * 2 + bit) * 4096);

    u_lds[lane] = u;
    __syncthreads();

    float s = 0.0f;
    #pragma unroll
    for (int g = 0; g < 16; ++g) {
      float4 q = Qm4[g * 64 + lane];                   // coalesced 16B/lane
      float4 uu = *(const float4*)&u_lds[g * 4];       // broadcast
      s = fmaf(q.x, uu.x, s);
      s = fmaf(q.y, uu.y, s);
      s = fmaf(q.z, uu.z, s);
      s = fmaf(q.w, uu.w, s);
    }
    __syncthreads();
    u = s;

    if ((t & 7) == 0) {  // renormalize every 8 steps (values only decay)
      float m = u;
      #pragma unroll
      for (int o = 32; o >= 1; o >>= 1) m = fmaxf(m, __shfl_xor(m, o));
      acc += __logf(m);
      u *= (1.0f / m);
    }
  }

  out[b * 64 + lane] = logf(u) + acc;
}

extern "C" void kernel_launch(void* const* d_in, const int* in_sizes, int n_in,
                              void* d_out, int out_size, void* d_ws, size_t ws_size,
                              hipStream_t stream) {
  const float* x     = (const float*)d_in[0];  // (512, 64)
  const float* theta = (const float*)d_in[1];  // (1, 64, 64, 64)
  const float* ulpa  = (const float*)d_in[2];  // (1, 63, 1, 64)
  float* out = (float*)d_out;                  // (512, 64, 1)

  float* Q    = (float*)d_ws;                  // 63*2*4096 floats
  float* pvar = Q + NSTEP * 2 * 4096;          // 2*64 floats

  hipLaunchKernelGGL(precompute_kernel, dim3(NSTEP), dim3(256), 0, stream,
                     theta, ulpa, Q, pvar);
  hipLaunchKernelGGL(chain_kernel, dim3(512), dim3(64), 0, stream,
                     x, Q, pvar, out);
}

// Round 2
// 98.839 us; speedup vs baseline: 1.0684x; 1.0684x over previous
//
#include <hip/hip_runtime.h>
#include <hip/hip_bf16.h>

// BATCH=512, INPUT_SIZE=64, ALPHA_DIM=64
// out[b,a] = log-semiring chain, folded right-to-left as matvecs in linear
// probability space. Q[t][var] precomputed; variant picked per batch from a
// 64-bit ballot mask of x.
//
// Q layout per (t,var): o = (j>>2)*256 + a*4 + (j&3)
//   => lane a loads float4 at Qm4[g*64 + a] covering j=4g..4g+3 (coalesced)

#define NSTEP 63

__global__ __launch_bounds__(256) void precompute_kernel(
    const float* __restrict__ theta, const float* __restrict__ ulpa,
    float* __restrict__ Q, float* __restrict__ pvar) {
  int t = blockIdx.x;  // 0..62
  __shared__ float tile[64][65];
  __shared__ float pa[64];
  int tid = threadIdx.x;

  const float4* th4 = (const float4*)(theta + t * 4096);
  #pragma unroll
  for (int k = 0; k < 4; ++k) {
    int i = tid + k * 256;
    float4 v = th4[i];
    int a = i >> 4;
    int j0 = (i & 15) * 4;
    tile[a][j0 + 0] = v.x;
    tile[a][j0 + 1] = v.y;
    tile[a][j0 + 2] = v.z;
    tile[a][j0 + 3] = v.w;
  }

  if (tid < 64) {
    float v = ulpa[t * 64 + tid];
    float m = v;
    #pragma unroll
    for (int o = 32; o >= 1; o >>= 1) m = fmaxf(m, __shfl_xor(m, o));
    float e = __expf(v - m);
    float s = e;
    #pragma unroll
    for (int o = 32; o >= 1; o >>= 1) s += __shfl_xor(s, o);
    pa[tid] = e / s;
  }
  __syncthreads();

  float* Q0 = Q + (t * 2 + 0) * 4096;
  float* Q1 = Q + (t * 2 + 1) * 4096;
  #pragma unroll
  for (int k = 0; k < 16; ++k) {
    int o = tid + k * 256;
    int g = o >> 8;
    int rem = o & 255;
    int a = rem >> 2;
    int d = rem & 3;
    int j = g * 4 + d;
    float th = tile[a][j];
    float sig = 1.0f / (1.0f + __expf(-th));
    float w = pa[j];
    Q1[o] = sig * w;
    Q0[o] = (1.0f - sig) * w;
  }

  if (t == 0 && tid < 64) {
    float th = theta[63 * 4096 + tid * 64 + 0];
    float sig = 1.0f / (1.0f + __expf(-th));
    pvar[64 + tid] = sig;
    pvar[0 + tid]  = 1.0f - sig;
  }
}

__global__ __launch_bounds__(64) void chain_kernel(
    const float* __restrict__ x, const float* __restrict__ Q,
    const float* __restrict__ pvar, float* __restrict__ out) {
  int b = blockIdx.x;     // 0..511
  int lane = threadIdx.x; // 0..63

  float xv = x[b * 64 + lane];
  unsigned long long mask = __ballot(xv != 0.0f);

  __shared__ __align__(16) float u_lds[64];

  float u = pvar[(int)((mask >> 63) & 1ull) * 64 + lane];
  float acc = 0.0f;

  float4 qa[16], qb[16];

  // prefetch t = 62 into qa
  {
    const float4* P = (const float4*)(Q + (62 * 2 + (int)((mask >> 62) & 1ull)) * 4096);
    #pragma unroll
    for (int g = 0; g < 16; ++g) qa[g] = P[g * 64 + lane];
  }

  // One step: broadcast u via LDS (single wave: no barrier needed — LDS ops
  // are program-ordered within a wave and the compiler's lgkmcnt wait covers
  // the write->read dep), prefetch step PT into PREG, 64 FMAs on 4
  // independent accumulators (dep chain 16 deep, not 64).
  #define STEP(QREG, PT, PREG)                                              \
    {                                                                       \
      u_lds[lane] = u;                                                      \
      if ((PT) >= 0) {                                                      \
        const float4* P = (const float4*)(Q + ((PT) * 2 +                   \
                              (int)((mask >> (PT)) & 1ull)) * 4096);        \
        _Pragma("unroll")                                                   \
        for (int g = 0; g < 16; ++g) PREG[g] = P[g * 64 + lane];            \
      }                                                                     \
      float s0 = 0.f, s1 = 0.f, s2 = 0.f, s3 = 0.f;                         \
      _Pragma("unroll")                                                     \
      for (int g = 0; g < 16; g += 4) {                                     \
        float4 q0 = QREG[g + 0], q1 = QREG[g + 1];                          \
        float4 q2 = QREG[g + 2], q3 = QREG[g + 3];                          \
        float4 u0 = *(const float4*)&u_lds[(g + 0) * 4];                    \
        float4 u1 = *(const float4*)&u_lds[(g + 1) * 4];                    \
        float4 u2 = *(const float4*)&u_lds[(g + 2) * 4];                    \
        float4 u3 = *(const float4*)&u_lds[(g + 3) * 4];                    \
        s0 = fmaf(q0.x, u0.x, s0); s0 = fmaf(q0.y, u0.y, s0);               \
        s0 = fmaf(q0.z, u0.z, s0); s0 = fmaf(q0.w, u0.w, s0);               \
        s1 = fmaf(q1.x, u1.x, s1); s1 = fmaf(q1.y, u1.y, s1);               \
        s1 = fmaf(q1.z, u1.z, s1); s1 = fmaf(q1.w, u1.w, s1);               \
        s2 = fmaf(q2.x, u2.x, s2); s2 = fmaf(q2.y, u2.y, s2);               \
        s2 = fmaf(q2.z, u2.z, s2); s2 = fmaf(q2.w, u2.w, s2);               \
        s3 = fmaf(q3.x, u3.x, s3); s3 = fmaf(q3.y, u3.y, s3);               \
        s3 = fmaf(q3.z, u3.z, s3); s3 = fmaf(q3.w, u3.w, s3);               \
      }                                                                     \
      u = (s0 + s1) + (s2 + s3);                                            \
    }

  // t = 62 .. 2 in pairs (qa: even-t snapshot, qb: odd), then t=0 leftover.
  for (int t = 62; t >= 2; t -= 2) {
    STEP(qa, t - 1, qb);          // step t, prefetch t-1
    STEP(qb, t - 2, qa);          // step t-1, prefetch t-2
    if (((t - 2) & 15) == 0 && (t - 2) != 0) {
      // renormalize: max decays >= 0.27^16 ~ 2^-30 per window -> f32-safe
      float m = u;
      #pragma unroll
      for (int o = 32; o >= 1; o >>= 1) m = fmaxf(m, __shfl_xor(m, o));
      acc += __logf(m);
      u *= (1.0f / m);
    }
  }
  STEP(qa, -1, qb);               // step t = 0, no prefetch
  #undef STEP

  out[b * 64 + lane] = logf(u) + acc;
}

extern "C" void kernel_launch(void* const* d_in, const int* in_sizes, int n_in,
                              void* d_out, int out_size, void* d_ws, size_t ws_size,
                              hipStream_t stream) {
  const float* x     = (const float*)d_in[0];  // (512, 64)
  const float* theta = (const float*)d_in[1];  // (1, 64, 64, 64)
  const float* ulpa  = (const float*)d_in[2];  // (1, 63, 1, 64)
  float* out = (float*)d_out;                  // (512, 64, 1)

  float* Q    = (float*)d_ws;                  // 63*2*4096 floats
  float* pvar = Q + NSTEP * 2 * 4096;          // 2*64 floats

  hipLaunchKernelGGL(precompute_kernel, dim3(NSTEP), dim3(256), 0, stream,
                     theta, ulpa, Q, pvar);
  hipLaunchKernelGGL(chain_kernel, dim3(512), dim3(64), 0, stream,
                     x, Q, pvar, out);
}